// Round 1
// baseline (1571.800 us; speedup 1.0000x reference)
//
#include <hip/hip_runtime.h>
#include <hip/hip_bf16.h>
#include <cstdint>

typedef __attribute__((ext_vector_type(8))) short short8;
typedef __attribute__((ext_vector_type(4))) float float4v;
typedef __attribute__((ext_vector_type(2))) unsigned int uint2v;

#define LOG2E 1.44269504088896340736f
#define LN2   0.69314718055994530942f

#if __has_builtin(__builtin_amdgcn_exp2f)
__device__ __forceinline__ float fexp2(float x){ return __builtin_amdgcn_exp2f(x); }
#else
__device__ __forceinline__ float fexp2(float x){ return exp2f(x); }
#endif
#if __has_builtin(__builtin_amdgcn_logf)
__device__ __forceinline__ float flog2(float x){ return __builtin_amdgcn_logf(x); }
#else
__device__ __forceinline__ float flog2(float x){ return log2f(x); }
#endif

// hhat = log2(1 + 2^zhat); biases pre-scaled by log2e so GEMM on hhat yields
// the next zhat directly (ln2 * log2e == 1 cancels).
__device__ __forceinline__ float softplus_hat(float zh){
  return flog2(1.0f + fexp2(zh));
}

// softplus output > 0 -> truncation (RTZ) to bf16 is a 1-instr shift.
__device__ __forceinline__ unsigned short bf16_trunc(float f){
  return (unsigned short)(__builtin_bit_cast(unsigned int, f) >> 16);
}

// pack two positive floats to a bf16 pair (lo in low half) via one v_perm_b32
__device__ __forceinline__ unsigned int bf16_pack2(float lo, float hi){
  return __builtin_amdgcn_perm(__builtin_bit_cast(unsigned int, hi),
                               __builtin_bit_cast(unsigned int, lo),
                               0x07060302u);
}

// h tile layout (per 32-row half-tile): addr(m,c) = m*264 + (m>>2)*16 + c.
//  * row stride 264 elems = 528 B == 0 mod 16 -> ds_read_b128 stays aligned.
//  * +16-elem skew per 4 rows keeps A-reads and packed b64 C-writes at the
//    wave64 minimum bank aliasing (analyzed: ~uniform 4 dword-accesses/bank).
#define HSTRIDE 264
#define MISTEP  4288                    // 16*264 + 4*16 (16-row mi step)
#define TSIZE   8576                    // elems per 32-row tile: 32*264+8*16

// ---------------------------------------------------------------------------
// Pre-pass: Wh [S,4,256,256] fp32 -> bf16 slabs Wt[s*4+l][kb][n][ki]
// (kb = k/32, ki = k%32). Frags read from GLOBAL: lanes {n,n+16,n+32,n+48}
// cover row n's 64B contiguously -> 1KB/wave-instr from L2.
// ---------------------------------------------------------------------------
__global__ void convert_wh(const float* __restrict__ Wh,
                           unsigned short* __restrict__ Wt){
  int e = blockIdx.x * 256 + threadIdx.x;          // 0 .. 2^21-1
  int n  = e & 255;
  int k  = (e >> 8) & 255;
  int sl = e >> 16;
  float v = Wh[e];
  __hip_bfloat16 h = __float2bfloat16(v);
  Wt[(sl << 16) + ((k >> 5) << 13) + (n << 5) + (k & 31)] =
      __builtin_bit_cast(unsigned short, h);
}

// OPERAND SWAP: W as A-operand, h as B-operand. Read addressing is identical
// (A row=lane&15 <-> B col=lane&15 symmetry), but D now holds 4 CONSECUTIVE n
// at fixed m per lane -> packed b64 h-writeback + trivial epilogue dot.
__device__ __forceinline__ float4v bf16_mfma(short8 a, short8 b, float4v c){
  return __builtin_amdgcn_mfma_f32_16x16x32_bf16(a, b, c, 0, 0, 0);
}

// layer-0 (K=3) for local rows 4j..4j+3 of one 32-row tile, column c
__device__ __forceinline__ void l0_iter(
    unsigned short* __restrict__ ht, const float4v* __restrict__ c4,
    int j, int c, float w0, float w1, float w2, float bb)
{
  float4v x0 = c4[j*3+0], x1 = c4[j*3+1], x2 = c4[j*3+2];
  float z0 = fmaf(x0.z, w2, fmaf(x0.y, w1, fmaf(x0.x, w0, bb)));
  float z1 = fmaf(x1.y, w2, fmaf(x1.x, w1, fmaf(x0.w, w0, bb)));
  float z2 = fmaf(x2.x, w2, fmaf(x1.w, w1, fmaf(x1.z, w0, bb)));
  float z3 = fmaf(x2.w, w2, fmaf(x2.z, w1, fmaf(x2.y, w0, bb)));
  ht[(4*j+0)*HSTRIDE + j*16 + c] = bf16_trunc(softplus_hat(z0));
  ht[(4*j+1)*HSTRIDE + j*16 + c] = bf16_trunc(softplus_hat(z1));
  ht[(4*j+2)*HSTRIDE + j*16 + c] = bf16_trunc(softplus_hat(z2));
  ht[(4*j+3)*HSTRIDE + j*16 + c] = bf16_trunc(softplus_hat(z3));
}

// softplus one frag (4 consecutive n at fixed m) of the OTHER tile and write
// one packed ds_write_b64. kb is a compile-time constant after unrolling.
__device__ __forceinline__ void sp_write(const float4v (&acc)[2][4],
    unsigned short* __restrict__ optr, int kb)
{
  const int mi = kb >> 2, ni = kb & 3;
  float4v v = acc[mi][ni];
  float s0 = softplus_hat(v.x), s1 = softplus_hat(v.y);
  float s2 = softplus_hat(v.z), s3 = softplus_hat(v.w);
  uint2v dd;
  dd.x = bf16_pack2(s0, s1);
  dd.y = bf16_pack2(s2, s3);
  *(uint2v*)(optr + mi*MISTEP + ni*16) = dd;
}

// softplus one frag of the OTHER tile and fold into the output dot
__device__ __forceinline__ void sp_dot(const float4v (&acc)[2][4],
    const float4v (&wv)[4], float (&p)[2], int kb)
{
  const int mi = kb >> 2, ni = kb & 3;
  float4v v = acc[mi][ni];
  p[mi] = fmaf(softplus_hat(v.x), wv[ni].x, p[mi]);
  p[mi] = fmaf(softplus_hat(v.y), wv[ni].y, p[mi]);
  p[mi] = fmaf(softplus_hat(v.z), wv[ni].z, p[mi]);
  p[mi] = fmaf(softplus_hat(v.w), wv[ni].w, p[mi]);
}

// ---------------------------------------------------------------------------
// One phase: K-loop (8 kb) of MFMAs for ONE 32-row tile, with `other(kb)`
// (the other tile's softplus/writeback or layer-0 chunk) interleaved per kb
// so the VALU pipe runs under the MFMA pipe within a single wave.
// B slots rotate continuously across phases: slot = (8*PH + kb) % 3; at
// kb 5..7 the freed slot prefetches the NEXT phase's kb 0..2 from bn.
// ---------------------------------------------------------------------------
template<int PH, bool LOADN, class F>
__device__ __forceinline__ void mfma_phase(
    const unsigned short* __restrict__ bb,
    const unsigned short* __restrict__ bn,
    const unsigned short* __restrict__ aptr,
    short8 (&bq)[3][4], float4v (&acc)[2][4], F&& other)
{
  short8 a0[2], a1[2];
  #pragma unroll
  for (int mi = 0; mi < 2; ++mi)
    a0[mi] = *(const short8*)(aptr + mi * MISTEP);
  #pragma unroll
  for (int kb = 0; kb < 8; ++kb) {
    short8* cur = (kb & 1) ? a1 : a0;
    short8* nxt = (kb & 1) ? a0 : a1;
    if (kb < 7) {                                  // A prefetch depth 1 (LDS)
      #pragma unroll
      for (int mi = 0; mi < 2; ++mi)
        nxt[mi] = *(const short8*)(aptr + (kb + 1) * 32 + mi * MISTEP);
    }
    const int slot = (8 * PH + kb) % 3;            // compile-time (unrolled)
    #pragma unroll
    for (int mi = 0; mi < 2; ++mi)
      #pragma unroll
      for (int ni = 0; ni < 4; ++ni)
        acc[mi][ni] = bf16_mfma(bq[slot][ni], cur[mi], acc[mi][ni]);
    if (kb < 5) {                                  // B depth-3, this phase
      #pragma unroll
      for (int ni = 0; ni < 4; ++ni)
        bq[slot][ni] = *(const short8*)(bb + (kb + 3) * 8192 + ni * 512);
    } else if (LOADN) {                            // next phase's kb 0..2
      #pragma unroll
      for (int ni = 0; ni < 4; ++ni)
        bq[slot][ni] = *(const short8*)(bn + (kb - 5) * 8192 + ni * 512);
    }
    other(kb);                                     // other tile's VALU chunk
  }
}

// ---------------------------------------------------------------------------
// Fused MLP, two phase-offset 32-row half-tiles per block:
//   P0: MFMA_A(W0slab) || layer0_B     P1: MFMA_B(W0) || softplus_A -> hA
//   P2: MFMA_A(W1)     || sp_B -> hB   ...   P7: MFMA_B(W3) || sp_dot_A
// 4 waves, wave tile 32m x 64n per phase, one series/block, s = blk&7.
// ---------------------------------------------------------------------------
__global__ __launch_bounds__(256, 2) void series_mlp(
    const float* __restrict__ coords,
    const float* __restrict__ W0, const float* __restrict__ b0,
    const float* __restrict__ bh,
    const float* __restrict__ Wout, const float* __restrict__ bout,
    const unsigned short* __restrict__ Wt,
    float* __restrict__ out)
{
  __shared__ __align__(16) unsigned short h_lds[2 * TSIZE];   // 34304 B
  __shared__ float cbuf[192];

  const int tid  = threadIdx.x;
  const int lane = tid & 63;
  const int wave = tid >> 6;
  const int s    = blockIdx.x & 7;          // series == XCD
  const int m0   = (blockIdx.x >> 3) * 64;  // 3125*64 == 200000 exactly

  const int q    = lane >> 4;
  const int lr   = lane & 15;
  const int colb = (wave << 6) + lr;

  // layer-0 weights for this thread's column (shared by both half-tiles)
  const int c = tid;
  const float w0  = W0[(s * 3 + 0) * 256 + c] * LOG2E;
  const float w1  = W0[(s * 3 + 1) * 256 + c] * LOG2E;
  const float w2  = W0[(s * 3 + 2) * 256 + c] * LOG2E;
  const float bb0 = b0[s * 256 + c] * LOG2E;

  if (tid < 192) cbuf[tid] = coords[m0 * 3 + tid];

  // W-frag lane base (A-operand after swap: row n = colb, k-octet q) and
  // initial 3-slot fill for the layer-0 slab (issued early to hide L2 lat).
  const unsigned short* bbase0 = Wt + ((s << 2) << 16) + (colb << 5) + (q << 3);
  short8 bq[3][4];
  #pragma unroll
  for (int i = 0; i < 3; ++i)
    #pragma unroll
    for (int ni = 0; ni < 4; ++ni)
      bq[i][ni] = *(const short8*)(bbase0 + i * 8192 + ni * 512);

  // h-frag lane base (B-operand: col m = lr + mi*16, k-octet q), per tile
  const unsigned short* aptrA = h_lds + lr * HSTRIDE + (lr >> 2) * 16 + (q << 3);
  const unsigned short* aptrB = aptrA + TSIZE;
  // packed C-write base: m = lr + mi*16, n = wave*64 + ni*16 + q*4 (+r)
  unsigned short* optrA = h_lds + lr * HSTRIDE + (lr >> 2) * 16 + (wave << 6) + (q << 2);
  unsigned short* optrB = optrA + TSIZE;

  const float* bh_s = bh + (s << 10);
  const float4v* c4 = (const float4v*)cbuf;

  __syncthreads();                      // cbuf ready
  #pragma unroll
  for (int j = 0; j < 8; ++j)           // layer 0, tile A (exposed prologue)
    l0_iter(h_lds, c4, j, c, w0, w1, w2, bb0);
  __syncthreads();                      // hA(0) ready

  float4v accA[2][4], accB[2][4];

  // bias init: D rows are n = wave*64 + ni*16 + q*4 + r -> float4 along n
#define INIT_ACC(ACC, LIDX)                                                   \
  {                                                                           \
    _Pragma("unroll")                                                         \
    for (int ni = 0; ni < 4; ++ni) {                                          \
      float4v b4 = *(const float4v*)(bh_s + (LIDX) * 256 + (wave << 6) +      \
                                     ni * 16 + (q << 2));                     \
      b4.x *= LOG2E; b4.y *= LOG2E; b4.z *= LOG2E; b4.w *= LOG2E;             \
      ACC[0][ni] = b4; ACC[1][ni] = b4;                                       \
    }                                                                         \
  }

  INIT_ACC(accA, 0)
  mfma_phase<0, true>(bbase0, bbase0, aptrA, bq, accA,
      [&](int j){ l0_iter(h_lds + TSIZE, c4 + 24, j, c, w0, w1, w2, bb0); });
  __syncthreads();                      // hB(0) ready

  INIT_ACC(accB, 0)
  mfma_phase<1, true>(bbase0, bbase0 + 65536, aptrB, bq, accB,
      [&](int kb){ sp_write(accA, optrA, kb); });
  __syncthreads();                      // hA(1) ready

  INIT_ACC(accA, 1)
  mfma_phase<2, true>(bbase0 + 65536, bbase0 + 65536, aptrA, bq, accA,
      [&](int kb){ sp_write(accB, optrB, kb); });
  __syncthreads();                      // hB(1) ready

  INIT_ACC(accB, 1)
  mfma_phase<3, true>(bbase0 + 65536, bbase0 + 2 * 65536, aptrB, bq, accB,
      [&](int kb){ sp_write(accA, optrA, kb); });
  __syncthreads();                      // hA(2) ready

  INIT_ACC(accA, 2)
  mfma_phase<4, true>(bbase0 + 2 * 65536, bbase0 + 2 * 65536, aptrA, bq, accA,
      [&](int kb){ sp_write(accB, optrB, kb); });
  __syncthreads();                      // hB(2) ready

  INIT_ACC(accB, 2)
  mfma_phase<5, true>(bbase0 + 2 * 65536, bbase0 + 3 * 65536, aptrB, bq, accB,
      [&](int kb){ sp_write(accA, optrA, kb); });
  __syncthreads();                      // hA(3) ready

  INIT_ACC(accA, 3)
  mfma_phase<6, true>(bbase0 + 3 * 65536, bbase0 + 3 * 65536, aptrA, bq, accA,
      [&](int kb){ sp_write(accB, optrB, kb); });
  __syncthreads();                      // hB(3) ready

  INIT_ACC(accB, 3)
  float4v wv[4];
  #pragma unroll
  for (int ni = 0; ni < 4; ++ni)
    wv[ni] = *(const float4v*)(Wout + (s << 8) + (wave << 6) + ni * 16 + (q << 2));
  float pA[2] = {0.f, 0.f}, pB[2] = {0.f, 0.f};

  mfma_phase<7, false>(bbase0 + 3 * 65536, bbase0, aptrB, bq, accB,
      [&](int kb){ sp_dot(accA, wv, pA, kb); });
  #pragma unroll
  for (int kb = 0; kb < 8; ++kb)        // tile B's dot (exposed epilogue)
    sp_dot(accB, wv, pB, kb);

  // reduce across q-groups (lanes l, l^16, l^32 cover the wave's 4 n-slices)
  pA[0] += __shfl_xor(pA[0], 16); pA[0] += __shfl_xor(pA[0], 32);
  pA[1] += __shfl_xor(pA[1], 16); pA[1] += __shfl_xor(pA[1], 32);
  pB[0] += __shfl_xor(pB[0], 16); pB[0] += __shfl_xor(pB[0], 32);
  pB[1] += __shfl_xor(pB[1], 16); pB[1] += __shfl_xor(pB[1], 32);

  // cross-wave reduce: red[m 0..63][wave 0..3] in hA's region (P7/EPI only
  // touch hB's region, and the post-P6 barrier fenced the last hA readers).
  float* red = (float*)h_lds;
  if (lane < 16) {
    red[(lr)      * 4 + wave] = pA[0];
    red[(16 + lr) * 4 + wave] = pA[1];
    red[(32 + lr) * 4 + wave] = pB[0];
    red[(48 + lr) * 4 + wave] = pB[1];
  }
  __syncthreads();
  if (tid < 64) {
    float4v r4 = ((const float4v*)red)[tid];
    float tot = (r4.x + r4.y) + (r4.z + r4.w);
    out[(m0 + tid) * 8 + s] = fmaf(LN2, tot, bout[s]);  // undo log2-domain
  }
#undef INIT_ACC
}

// ---------------------------------------------------------------------------
// Fallback (scratch-free), fp32 VALU — only if ws_size < 4 MiB.
// ---------------------------------------------------------------------------
__global__ __launch_bounds__(256) void series_mlp_slow(
    const float* __restrict__ coords,
    const float* __restrict__ W0, const float* __restrict__ b0,
    const float* __restrict__ Wh, const float* __restrict__ bh,
    const float* __restrict__ Wout, const float* __restrict__ bout,
    float* __restrict__ out)
{
  __shared__ float hh[64 * 256];
  __shared__ float cbuf[192];
  __shared__ float red[256];
  const int tid = threadIdx.x;
  const int s   = blockIdx.y;
  const int m0  = blockIdx.x * 64;

  if (tid < 192) cbuf[tid] = coords[m0 * 3 + tid];
  __syncthreads();
  {
    const float w0 = W0[(s * 3 + 0) * 256 + tid];
    const float w1 = W0[(s * 3 + 1) * 256 + tid];
    const float w2 = W0[(s * 3 + 2) * 256 + tid];
    const float bb = b0[s * 256 + tid];
    for (int m = 0; m < 64; ++m) {
      float z = fmaf(cbuf[m * 3 + 2], w2,
                fmaf(cbuf[m * 3 + 1], w1,
                fmaf(cbuf[m * 3 + 0], w0, bb)));
      hh[m * 256 + tid] = LN2 * softplus_hat(z * LOG2E);
    }
  }
  __syncthreads();

  for (int l = 0; l < 4; ++l) {
    const float* W = Wh + (((s << 2) + l) << 16);
    const float bb = bh[((s << 2) + l) * 256 + tid];
    float acc[64];
    #pragma unroll
    for (int m = 0; m < 64; ++m) acc[m] = bb;
    for (int kc = 0; kc < 64; ++kc) {
      float w0 = W[(kc * 4 + 0) * 256 + tid];
      float w1 = W[(kc * 4 + 1) * 256 + tid];
      float w2 = W[(kc * 4 + 2) * 256 + tid];
      float w3 = W[(kc * 4 + 3) * 256 + tid];
      #pragma unroll
      for (int m = 0; m < 64; ++m) {
        float4v hv = *(const float4v*)&hh[m * 256 + kc * 4];
        acc[m] = fmaf(hv.w, w3, fmaf(hv.z, w2,
                 fmaf(hv.y, w1, fmaf(hv.x, w0, acc[m]))));
      }
    }
    __syncthreads();
    #pragma unroll
    for (int m = 0; m < 64; ++m)
      hh[m * 256 + tid] = LN2 * softplus_hat(acc[m] * LOG2E);
    __syncthreads();
  }
  {
    const int m = tid >> 2, qq = tid & 3;
    const float* wv = Wout + (s << 8);
    float sum = 0.f;
    for (int i = 0; i < 16; ++i) {
      int kk = (qq << 6) + ((((tid & 15) + i) << 2) & 63);
      float4v hv = *(const float4v*)&hh[m * 256 + kk];
      sum += hv.x * wv[kk] + hv.y * wv[kk + 1] + hv.z * wv[kk + 2] + hv.w * wv[kk + 3];
    }
    red[tid] = sum;
    __syncthreads();
    if (tid < 64)
      out[(m0 + tid) * 8 + s] =
          red[tid * 4] + red[tid * 4 + 1] + red[tid * 4 + 2] + red[tid * 4 + 3] + bout[s];
  }
}

extern "C" void kernel_launch(void* const* d_in, const int* in_sizes, int n_in,
                              void* d_out, int out_size, void* d_ws, size_t ws_size,
                              hipStream_t stream) {
  const float* coords = (const float*)d_in[0];
  const float* W0     = (const float*)d_in[1];
  const float* b0     = (const float*)d_in[2];
  const float* Wh     = (const float*)d_in[3];
  const float* bh     = (const float*)d_in[4];
  const float* Wout   = (const float*)d_in[5];
  const float* bout   = (const float*)d_in[6];
  float* out = (float*)d_out;

  const size_t WT_BYTES = (size_t)8 * 4 * 256 * 256 * 2;   // 4 MiB bf16 slabs
  if (ws_size >= WT_BYTES) {
    unsigned short* Wt = (unsigned short*)d_ws;
    convert_wh<<<8192, 256, 0, stream>>>(Wh, Wt);
    series_mlp<<<dim3(25000), dim3(256), 0, stream>>>(
        coords, W0, b0, bh, Wout, bout, Wt, out);
  } else {
    series_mlp_slow<<<dim3(3125, 8), dim3(256), 0, stream>>>(
        coords, W0, b0, Wh, bh, Wout, bout, out);
  }
  // second tuple output: echo coords
  hipMemcpyAsync(out + (size_t)200000 * 8, coords,
                 (size_t)200000 * 3 * sizeof(float),
                 hipMemcpyDeviceToDevice, stream);
}

// Round 2
// 931.803 us; speedup vs baseline: 1.6868x; 1.6868x over previous
//
#include <hip/hip_runtime.h>
#include <hip/hip_bf16.h>
#include <cstdint>

typedef __attribute__((ext_vector_type(8))) short short8;
typedef __attribute__((ext_vector_type(4))) float float4v;

#define LOG2E 1.44269504088896340736f
#define LN2   0.69314718055994530942f

#if __has_builtin(__builtin_amdgcn_exp2f)
__device__ __forceinline__ float fexp2(float x){ return __builtin_amdgcn_exp2f(x); }
#else
__device__ __forceinline__ float fexp2(float x){ return exp2f(x); }
#endif
#if __has_builtin(__builtin_amdgcn_logf)
__device__ __forceinline__ float flog2(float x){ return __builtin_amdgcn_logf(x); }
#else
__device__ __forceinline__ float flog2(float x){ return log2f(x); }
#endif

// hhat = log2(1 + 2^zhat); biases pre-scaled by log2e so GEMM on hhat yields
// the next zhat directly (ln2 * log2e == 1 cancels).
__device__ __forceinline__ float softplus_hat(float zh){
  return flog2(1.0f + fexp2(zh));
}

// softplus output > 0 -> truncation (RTZ) to bf16 is a 1-instr shift.
__device__ __forceinline__ unsigned short bf16_trunc(float f){
  return (unsigned short)(__builtin_bit_cast(unsigned int, f) >> 16);
}

// h tile layout (per 64-row tile): addr(m,c) = m*264 + (m>>2)*16 + c elems.
// (round-0 champion layout, unchanged: 528 B row stride keeps ds_read_b128
// aligned; +16-elem skew per 4 rows keeps A-reads and scalar b16 C-writes at
// the wave64 2-lanes/bank minimum.)
#define HSTRIDE 264
#define MISTEP  4288                    // 16*264 + 4*16
#define HSIZE   (64 * 264 + 16 * 16)    // 17152 elems = 34304 B per tile

// ---------------------------------------------------------------------------
// Pre-pass: Wh [S,4,256,256] fp32 -> bf16 slabs Wt[s*4+l][kb][n][ki]
// (kb = k/32, ki = k%32). B-frags read from GLOBAL: lanes {n,n+16,n+32,n+48}
// cover row n's 64B contiguously -> 1KB/wave-instr from L2.
// ---------------------------------------------------------------------------
__global__ void convert_wh(const float* __restrict__ Wh,
                           unsigned short* __restrict__ Wt){
  int e = blockIdx.x * 256 + threadIdx.x;          // 0 .. 2^21-1
  int n  = e & 255;
  int k  = (e >> 8) & 255;
  int sl = e >> 16;
  float v = Wh[e];
  __hip_bfloat16 h = __float2bfloat16(v);
  Wt[(sl << 16) + ((k >> 5) << 13) + (n << 5) + (k & 31)] =
      __builtin_bit_cast(unsigned short, h);
}

__device__ __forceinline__ float4v bf16_mfma(short8 a, short8 b, float4v c){
  return __builtin_amdgcn_mfma_f32_16x16x32_bf16(a, b, c, 0, 0, 0);
}

// layer-0 (K=3) for rows 4j..4j+3 of one 64-row tile, column c
__device__ __forceinline__ void l0_rows(
    unsigned short* __restrict__ ht, const float4v* __restrict__ c4,
    int j, int c, float w0, float w1, float w2, float bb)
{
  float4v x0 = c4[j*3+0], x1 = c4[j*3+1], x2 = c4[j*3+2];
  float z0 = fmaf(x0.z, w2, fmaf(x0.y, w1, fmaf(x0.x, w0, bb)));
  float z1 = fmaf(x1.y, w2, fmaf(x1.x, w1, fmaf(x0.w, w0, bb)));
  float z2 = fmaf(x2.x, w2, fmaf(x1.w, w1, fmaf(x1.z, w0, bb)));
  float z3 = fmaf(x2.w, w2, fmaf(x2.z, w1, fmaf(x2.y, w0, bb)));
  ht[(4*j+0)*HSTRIDE + j*16 + c] = bf16_trunc(softplus_hat(z0));
  ht[(4*j+1)*HSTRIDE + j*16 + c] = bf16_trunc(softplus_hat(z1));
  ht[(4*j+2)*HSTRIDE + j*16 + c] = bf16_trunc(softplus_hat(z2));
  ht[(4*j+3)*HSTRIDE + j*16 + c] = bf16_trunc(softplus_hat(z3));
}

// softplus + write-back of 2 frags (idx 2kb, 2kb+1) of the OTHER tile's acc.
// kb is compile-time after unrolling -> pure base+immediate LDS stores.
__device__ __forceinline__ void sp2(const float4v (&acc)[4][4],
    unsigned short* __restrict__ cptr, int kb)
{
  #pragma unroll
  for (int t = 0; t < 2; ++t) {
    const int idx = kb * 2 + t, mi = idx >> 2, ni = idx & 3;
    float4v v = acc[mi][ni];
    #pragma unroll
    for (int r = 0; r < 4; ++r)
      cptr[mi * MISTEP + r * HSTRIDE + ni * 16] = bf16_trunc(softplus_hat(v[r]));
  }
}

// softplus + output-dot of 2 frags of the OTHER tile's acc (last layer)
__device__ __forceinline__ void spdot2(const float4v (&acc)[4][4],
    const float (&wv)[4], float (&p)[16], int kb)
{
  #pragma unroll
  for (int t = 0; t < 2; ++t) {
    const int idx = kb * 2 + t, mi = idx >> 2, ni = idx & 3;
    float4v v = acc[mi][ni];
    #pragma unroll
    for (int r = 0; r < 4; ++r)
      p[mi * 4 + r] = fmaf(softplus_hat(v[r]), wv[ni], p[mi * 4 + r]);
  }
}

// ---------------------------------------------------------------------------
// One phase = round-0's K-loop VERBATIM (16 mfma/kb, depth-3 rotating B
// prefetch, slot=(8*PH+kb)%3 continuous across all 8 phases; kb 5..7 prefetch
// the NEXT phase's kb 0..2 from bn) + `other(kb)`: the other tile's VALU
// chunk (softplus/writeback, layer-0, or output dot) interleaved per kb so
// the VALU pipe runs under the MFMA pipe within each wave.
// ---------------------------------------------------------------------------
template<int PH, bool LOADN, class F>
__device__ __forceinline__ void mfma_phase(
    const unsigned short* __restrict__ bb,   // this phase's slab + lane offset
    const unsigned short* __restrict__ bn,   // next phase's slab + lane offset
    const unsigned short* __restrict__ aptr, // h tile + lane A-base
    short8 (&bq)[3][4], float4v (&acc)[4][4], F&& other)
{
  short8 a0[4], a1[4];
  #pragma unroll
  for (int mi = 0; mi < 4; ++mi)
    a0[mi] = *(const short8*)(aptr + mi * MISTEP);

  #pragma unroll
  for (int kb = 0; kb < 8; ++kb) {
    short8* cur = (kb & 1) ? a1 : a0;
    short8* nxt = (kb & 1) ? a0 : a1;
    if (kb < 7) {                                  // A prefetch depth 1 (LDS)
      #pragma unroll
      for (int mi = 0; mi < 4; ++mi)
        nxt[mi] = *(const short8*)(aptr + (kb + 1) * 32 + mi * MISTEP);
    }
    const int slot = (8 * PH + kb) % 3;            // compile-time (unrolled)
    #pragma unroll
    for (int mi = 0; mi < 4; ++mi)
      #pragma unroll
      for (int ni = 0; ni < 4; ++ni)
        acc[mi][ni] = bf16_mfma(cur[mi], bq[slot][ni], acc[mi][ni]);
    if (kb < 5) {                                  // B depth-3, this phase
      #pragma unroll
      for (int ni = 0; ni < 4; ++ni)
        bq[slot][ni] = *(const short8*)(bb + (kb + 3) * 8192 + ni * 512);
    } else if (LOADN) {                            // next phase's kb 0..2
      #pragma unroll
      for (int ni = 0; ni < 4; ++ni)
        bq[slot][ni] = *(const short8*)(bn + (kb - 5) * 8192 + ni * 512);
    }
    other(kb);                                     // other tile's VALU chunk
  }
}

// ---------------------------------------------------------------------------
// Fused MLP: one workgroup owns TWO 64-row tiles (128 rows) in anti-phase.
// Each phase: K-loop(tile X, layer l) with tile Y's softplus interleaved.
// B traffic per output row is UNCHANGED vs round-0 (2 phases/layer over 2x
// rows). 4 waves, wave tile 64m x 64n, one series/block, s = blk&7.
// LDS: 2 x 34304 B tiles + cbuf = 70 KB -> 2 blocks/CU (140/160 KB).
// ---------------------------------------------------------------------------
__global__ __launch_bounds__(256, 2) void series_mlp(
    const float* __restrict__ coords,
    const float* __restrict__ W0, const float* __restrict__ b0,
    const float* __restrict__ bh,
    const float* __restrict__ Wout, const float* __restrict__ bout,
    const unsigned short* __restrict__ Wt,
    float* __restrict__ out)
{
  __shared__ __align__(16) unsigned short h_lds[2 * HSIZE];   // 68608 B
  __shared__ float cbuf[384];

  const int tid  = threadIdx.x;
  const int lane = tid & 63;
  const int wave = tid >> 6;
  const int s    = blockIdx.x & 7;           // series == XCD
  const int m0   = (blockIdx.x >> 3) * 128;  // 1563 m-blocks; tail tile1 dead

  const int q    = lane >> 4;
  const int lr   = lane & 15;
  const int colb = (wave << 6) + lr;

  // coords for 128 rows (tail block: clamp index -> finite garbage, unwritten)
  {
    int i1 = m0 * 3 + tid;
    int i2 = i1 + 256;
    cbuf[tid] = coords[i1 < 599999 ? i1 : 599999];
    if (tid < 128) cbuf[tid + 256] = coords[i2 < 599999 ? i2 : 599999];
  }

  // layer-0 weights for this thread's column (shared by both tiles)
  const int c = tid;
  const float w0  = W0[(s * 3 + 0) * 256 + c] * LOG2E;
  const float w1  = W0[(s * 3 + 1) * 256 + c] * LOG2E;
  const float w2  = W0[(s * 3 + 2) * 256 + c] * LOG2E;
  const float bb0 = b0[s * 256 + c] * LOG2E;

  // B-frag lane base + initial 3-slot fill (issued early: hides L2 latency
  // under the layer-0 VALU work)
  const unsigned short* bbase0 = Wt + ((s << 2) << 16) + (colb << 5) + (q << 3);
  short8 bq[3][4];
  #pragma unroll
  for (int i = 0; i < 3; ++i)
    #pragma unroll
    for (int ni = 0; ni < 4; ++ni)
      bq[i][ni] = *(const short8*)(bbase0 + i * 8192 + ni * 512);

  // A-frag / C-write lane bases per tile (round-0 addressing, verbatim)
  const unsigned short* aptrA = h_lds + lr * HSTRIDE + (lr >> 2) * 16 + (q << 3);
  const unsigned short* aptrB = aptrA + HSIZE;
  unsigned short* cptrA = h_lds + q * 1072 + colb;
  unsigned short* cptrB = cptrA + HSIZE;

  const float* bh_s = bh + (s << 10);
  const float4v* c4 = (const float4v*)cbuf;

  __syncthreads();                      // cbuf ready
  #pragma unroll
  for (int j = 0; j < 16; ++j)          // layer 0, tile A (exposed prologue)
    l0_rows(h_lds, c4, j, c, w0, w1, w2, bb0);
  __syncthreads();                      // hA(0) ready

  float4v accA[4][4], accB[4][4];

#define INIT_ACC(ACC, LIDX)                                                   \
  {                                                                           \
    float bias[4];                                                            \
    _Pragma("unroll")                                                         \
    for (int ni = 0; ni < 4; ++ni)                                            \
      bias[ni] = bh_s[(LIDX) * 256 + colb + ni * 16] * LOG2E;                 \
    _Pragma("unroll")                                                         \
    for (int mi = 0; mi < 4; ++mi)                                            \
      _Pragma("unroll")                                                       \
      for (int ni = 0; ni < 4; ++ni)                                          \
        ACC[mi][ni] = (float4v){bias[ni], bias[ni], bias[ni], bias[ni]};      \
  }

  const unsigned short* B0 = bbase0;
  const unsigned short* B1 = bbase0 + 65536;
  const unsigned short* B2 = bbase0 + 2 * 65536;
  const unsigned short* B3 = bbase0 + 3 * 65536;

  // P0: K(tA, l0) || layer-0 for tile B (2 row-quads per kb)
  INIT_ACC(accA, 0)
  mfma_phase<0, true>(B0, B0, aptrA, bq, accA, [&](int kb){
    l0_rows(h_lds + HSIZE, c4 + 48, 2 * kb + 0, c, w0, w1, w2, bb0);
    l0_rows(h_lds + HSIZE, c4 + 48, 2 * kb + 1, c, w0, w1, w2, bb0);
  });
  __syncthreads();                      // hB(0) ready

  // P1: K(tB, l0) || softplus(accA) -> hA(1)
  INIT_ACC(accB, 0)
  mfma_phase<1, true>(B0, B1, aptrB, bq, accB,
      [&](int kb){ sp2(accA, cptrA, kb); });
  __syncthreads();                      // hA(1) ready

  // P2: K(tA, l1) || softplus(accB) -> hB(1)
  INIT_ACC(accA, 1)
  mfma_phase<2, true>(B1, B1, aptrA, bq, accA,
      [&](int kb){ sp2(accB, cptrB, kb); });
  __syncthreads();                      // hB(1) ready

  // P3: K(tB, l1) || softplus(accA) -> hA(2)
  INIT_ACC(accB, 1)
  mfma_phase<3, true>(B1, B2, aptrB, bq, accB,
      [&](int kb){ sp2(accA, cptrA, kb); });
  __syncthreads();                      // hA(2) ready

  // P4: K(tA, l2) || softplus(accB) -> hB(2)
  INIT_ACC(accA, 2)
  mfma_phase<4, true>(B2, B2, aptrA, bq, accA,
      [&](int kb){ sp2(accB, cptrB, kb); });
  __syncthreads();                      // hB(2) ready

  // P5: K(tB, l2) || softplus(accA) -> hA(3)
  INIT_ACC(accB, 2)
  mfma_phase<5, true>(B2, B3, aptrB, bq, accB,
      [&](int kb){ sp2(accA, cptrA, kb); });
  __syncthreads();                      // hA(3) ready

  // P6: K(tA, l3) || softplus(accB) -> hB(3)
  INIT_ACC(accA, 3)
  mfma_phase<6, true>(B3, B3, aptrA, bq, accA,
      [&](int kb){ sp2(accB, cptrB, kb); });
  __syncthreads();                      // hB(3) ready

  // P7: K(tB, l3) || softplus+output-dot of accA
  INIT_ACC(accB, 3)
  float wv[4];
  #pragma unroll
  for (int ni = 0; ni < 4; ++ni)
    wv[ni] = Wout[(s << 8) + colb + ni * 16];
  float pA[16], pB[16];
  #pragma unroll
  for (int i = 0; i < 16; ++i) pA[i] = 0.f;
  mfma_phase<7, false>(B3, B3, aptrB, bq, accB,
      [&](int kb){ spdot2(accA, wv, pA, kb); });

  #pragma unroll
  for (int i = 0; i < 16; ++i) pB[i] = 0.f;
  #pragma unroll
  for (int kb = 0; kb < 8; ++kb)        // tile B's dot (exposed epilogue)
    spdot2(accB, wv, pB, kb);

  // cross-wave reduce: 2 regions of 64 rows x 64 partials (stride-68 pad).
  // Barrier first: other waves may still be doing P7 A-reads from hB.
  __syncthreads();
  float* redA = (float*)h_lds;
  float* redB = redA + 64 * 68;
  #pragma unroll
  for (int mi = 0; mi < 4; ++mi)
    #pragma unroll
    for (int r = 0; r < 4; ++r) {
      int row = mi * 16 + (q << 2) + r;
      redA[row * 68 + (wave << 4) + lr] = pA[mi * 4 + r];
      redB[row * 68 + (wave << 4) + lr] = pB[mi * 4 + r];
    }
  __syncthreads();

  if (tid < 128) {
    const int t = tid & 63;
    const float* red = (tid < 64) ? redA : redB;
    const float4v* rr = (const float4v*)&red[t * 68];
    float4v a = rr[0];
    #pragma unroll
    for (int i = 1; i < 16; ++i) {
      float4v b = rr[i];
      a.x += b.x; a.y += b.y; a.z += b.z; a.w += b.w;
    }
    float tot = (a.x + a.y) + (a.z + a.w);
    int row = m0 + ((tid >> 6) << 6) + t;
    if (row < 200000)
      out[row * 8 + s] = fmaf(LN2, tot, bout[s]);  // undo log2-domain
  }
#undef INIT_ACC
}

// ---------------------------------------------------------------------------
// Fallback (scratch-free), fp32 VALU — only if ws_size < 4 MiB.
// ---------------------------------------------------------------------------
__global__ __launch_bounds__(256) void series_mlp_slow(
    const float* __restrict__ coords,
    const float* __restrict__ W0, const float* __restrict__ b0,
    const float* __restrict__ Wh, const float* __restrict__ bh,
    const float* __restrict__ Wout, const float* __restrict__ bout,
    float* __restrict__ out)
{
  __shared__ float hh[64 * 256];
  __shared__ float cbuf[192];
  __shared__ float red[256];
  const int tid = threadIdx.x;
  const int s   = blockIdx.y;
  const int m0  = blockIdx.x * 64;

  if (tid < 192) cbuf[tid] = coords[m0 * 3 + tid];
  __syncthreads();
  {
    const float w0 = W0[(s * 3 + 0) * 256 + tid];
    const float w1 = W0[(s * 3 + 1) * 256 + tid];
    const float w2 = W0[(s * 3 + 2) * 256 + tid];
    const float bb = b0[s * 256 + tid];
    for (int m = 0; m < 64; ++m) {
      float z = fmaf(cbuf[m * 3 + 2], w2,
                fmaf(cbuf[m * 3 + 1], w1,
                fmaf(cbuf[m * 3 + 0], w0, bb)));
      hh[m * 256 + tid] = LN2 * softplus_hat(z * LOG2E);
    }
  }
  __syncthreads();

  for (int l = 0; l < 4; ++l) {
    const float* W = Wh + (((s << 2) + l) << 16);
    const float bb = bh[((s << 2) + l) * 256 + tid];
    float acc[64];
    #pragma unroll
    for (int m = 0; m < 64; ++m) acc[m] = bb;
    for (int kc = 0; kc < 64; ++kc) {
      float w0 = W[(kc * 4 + 0) * 256 + tid];
      float w1 = W[(kc * 4 + 1) * 256 + tid];
      float w2 = W[(kc * 4 + 2) * 256 + tid];
      float w3 = W[(kc * 4 + 3) * 256 + tid];
      #pragma unroll
      for (int m = 0; m < 64; ++m) {
        float4v hv = *(const float4v*)&hh[m * 256 + kc * 4];
        acc[m] = fmaf(hv.w, w3, fmaf(hv.z, w2,
                 fmaf(hv.y, w1, fmaf(hv.x, w0, acc[m]))));
      }
    }
    __syncthreads();
    #pragma unroll
    for (int m = 0; m < 64; ++m)
      hh[m * 256 + tid] = LN2 * softplus_hat(acc[m] * LOG2E);
    __syncthreads();
  }
  {
    const int m = tid >> 2, qq = tid & 3;
    const float* wv = Wout + (s << 8);
    float sum = 0.f;
    for (int i = 0; i < 16; ++i) {
      int kk = (qq << 6) + ((((tid & 15) + i) << 2) & 63);
      float4v hv = *(const float4v*)&hh[m * 256 + kk];
      sum += hv.x * wv[kk] + hv.y * wv[kk + 1] + hv.z * wv[kk + 2] + hv.w * wv[kk + 3];
    }
    red[tid] = sum;
    __syncthreads();
    if (tid < 64)
      out[(m0 + tid) * 8 + s] =
          red[tid * 4] + red[tid * 4 + 1] + red[tid * 4 + 2] + red[tid * 4 + 3] + bout[s];
  }
}

extern "C" void kernel_launch(void* const* d_in, const int* in_sizes, int n_in,
                              void* d_out, int out_size, void* d_ws, size_t ws_size,
                              hipStream_t stream) {
  const float* coords = (const float*)d_in[0];
  const float* W0     = (const float*)d_in[1];
  const float* b0     = (const float*)d_in[2];
  const float* Wh     = (const float*)d_in[3];
  const float* bh     = (const float*)d_in[4];
  const float* Wout   = (const float*)d_in[5];
  const float* bout   = (const float*)d_in[6];
  float* out = (float*)d_out;

  const size_t WT_BYTES = (size_t)8 * 4 * 256 * 256 * 2;   // 4 MiB bf16 slabs
  if (ws_size >= WT_BYTES) {
    unsigned short* Wt = (unsigned short*)d_ws;
    convert_wh<<<8192, 256, 0, stream>>>(Wh, Wt);
    // 1563 m-blocks x 128 rows x 8 series; 1562*128+64 = 200000 (tail tile1 dead)
    series_mlp<<<dim3(12504), dim3(256), 0, stream>>>(
        coords, W0, b0, bh, Wout, bout, Wt, out);
  } else {
    series_mlp_slow<<<dim3(3125, 8), dim3(256), 0, stream>>>(
        coords, W0, b0, Wh, bh, Wout, bout, out);
  }
  // second tuple output: echo coords
  hipMemcpyAsync(out + (size_t)200000 * 8, coords,
                 (size_t)200000 * 3 * sizeof(float),
                 hipMemcpyDeviceToDevice, stream);
}

// Round 3
// 904.744 us; speedup vs baseline: 1.7373x; 1.0299x over previous
//
#include <hip/hip_runtime.h>
#include <hip/hip_bf16.h>
#include <cstdint>

typedef __attribute__((ext_vector_type(8))) short short8;
typedef __attribute__((ext_vector_type(4))) float float4v;

#define LOG2E 1.44269504088896340736f
#define LN2   0.69314718055994530942f

#if __has_builtin(__builtin_amdgcn_exp2f)
__device__ __forceinline__ float fexp2(float x){ return __builtin_amdgcn_exp2f(x); }
#else
__device__ __forceinline__ float fexp2(float x){ return exp2f(x); }
#endif
#if __has_builtin(__builtin_amdgcn_logf)
__device__ __forceinline__ float flog2(float x){ return __builtin_amdgcn_logf(x); }
#else
__device__ __forceinline__ float flog2(float x){ return log2f(x); }
#endif

// hhat = log2(1 + 2^zhat); biases pre-scaled by log2e so GEMM on hhat yields
// the next zhat directly (ln2 * log2e == 1 cancels).
__device__ __forceinline__ float softplus_hat(float zh){
  return flog2(1.0f + fexp2(zh));
}

// softplus output > 0 -> truncation (RTZ) to bf16 is a 1-instr shift.
__device__ __forceinline__ unsigned short bf16_trunc(float f){
  return (unsigned short)(__builtin_bit_cast(unsigned int, f) >> 16);
}

// h tile layout (per 64-row tile): addr(m,c) = m*264 + (m>>2)*16 + c elems.
// (round-0 champion layout, unchanged: 528 B row stride keeps ds_read_b128
// aligned; +16-elem skew per 4 rows keeps A-reads and scalar b16 C-writes at
// the wave64 2-lanes/bank minimum.)
#define HSTRIDE 264
#define MISTEP  4288                    // 16*264 + 4*16
#define HSIZE   (64 * 264 + 16 * 16)    // 17152 elems = 34304 B per tile

// ---------------------------------------------------------------------------
// Pre-pass: Wh [S,4,256,256] fp32 -> bf16 slabs Wt[s*4+l][kb][n][ki]
// (kb = k/32, ki = k%32). B-frags read from GLOBAL: lanes {n,n+16,n+32,n+48}
// cover row n's 64B contiguously -> 1KB/wave-instr from L2.
// ---------------------------------------------------------------------------
__global__ void convert_wh(const float* __restrict__ Wh,
                           unsigned short* __restrict__ Wt){
  int e = blockIdx.x * 256 + threadIdx.x;          // 0 .. 2^21-1
  int n  = e & 255;
  int k  = (e >> 8) & 255;
  int sl = e >> 16;
  float v = Wh[e];
  __hip_bfloat16 h = __float2bfloat16(v);
  Wt[(sl << 16) + ((k >> 5) << 13) + (n << 5) + (k & 31)] =
      __builtin_bit_cast(unsigned short, h);
}

__device__ __forceinline__ float4v bf16_mfma(short8 a, short8 b, float4v c){
  return __builtin_amdgcn_mfma_f32_16x16x32_bf16(a, b, c, 0, 0, 0);
}

// layer-0 (K=3) for rows 4j..4j+3 of one 64-row tile, column c
__device__ __forceinline__ void l0_rows(
    unsigned short* __restrict__ ht, const float4v* __restrict__ c4,
    int j, int c, float w0, float w1, float w2, float bb)
{
  float4v x0 = c4[j*3+0], x1 = c4[j*3+1], x2 = c4[j*3+2];
  float z0 = fmaf(x0.z, w2, fmaf(x0.y, w1, fmaf(x0.x, w0, bb)));
  float z1 = fmaf(x1.y, w2, fmaf(x1.x, w1, fmaf(x0.w, w0, bb)));
  float z2 = fmaf(x2.x, w2, fmaf(x1.w, w1, fmaf(x1.z, w0, bb)));
  float z3 = fmaf(x2.w, w2, fmaf(x2.z, w1, fmaf(x2.y, w0, bb)));
  ht[(4*j+0)*HSTRIDE + j*16 + c] = bf16_trunc(softplus_hat(z0));
  ht[(4*j+1)*HSTRIDE + j*16 + c] = bf16_trunc(softplus_hat(z1));
  ht[(4*j+2)*HSTRIDE + j*16 + c] = bf16_trunc(softplus_hat(z2));
  ht[(4*j+3)*HSTRIDE + j*16 + c] = bf16_trunc(softplus_hat(z3));
}

// softplus + write-back of 2 ELEMENTS (substep granularity) of the OTHER
// tile's acc. Frag idx = 2*kb + (sub>>1), elements r0..r0+1, r0 = (sub&1)*2.
// kb,sub compile-time after unrolling -> pure base+immediate LDS stores.
__device__ __forceinline__ void sp2s(const float4v (&acc)[4][4],
    unsigned short* __restrict__ cptr, int kb, int sub)
{
  const int idx = kb * 2 + (sub >> 1);
  const int mi = idx >> 2, ni = idx & 3;
  const int r0 = (sub & 1) * 2;
  float4v v = acc[mi][ni];
  #pragma unroll
  for (int r = r0; r < r0 + 2; ++r)
    cptr[mi * MISTEP + r * HSTRIDE + ni * 16] = bf16_trunc(softplus_hat(v[r]));
}

// softplus + output-dot of 2 elements of the OTHER tile's acc (last layer)
__device__ __forceinline__ void spdot2s(const float4v (&acc)[4][4],
    const float (&wv)[4], float (&p)[16], int kb, int sub)
{
  const int idx = kb * 2 + (sub >> 1);
  const int mi = idx >> 2, ni = idx & 3;
  const int r0 = (sub & 1) * 2;
  float4v v = acc[mi][ni];
  #pragma unroll
  for (int r = r0; r < r0 + 2; ++r)
    p[mi * 4 + r] = fmaf(softplus_hat(v[r]), wv[ni], p[mi * 4 + r]);
}

// ---------------------------------------------------------------------------
// One phase = round-2's K-loop split into 4 SUBSTEPS per kb, with
// sched_barrier(0) pins so the emitted order is a fine-grain
// {4 MFMA + mem-issue} / {~2 softplus elems} alternation. Rationale: the
// round-2 emission clumped per-kb convoys (16 MFMA then 8-elem softplus);
// in-order waves then feed only one pipe at a time and MfmaUtil+VALUBusy
// stay additive (40+50). Fine alternation lets the 2 resident waves/SIMD
// slot into opposite pipes (matrix vs VALU/trans) concurrently.
// Memory issue distance is preserved (A-prefetch sub 1 -> used next kb;
// B depth-3 global prefetch sub 3 -> used 3 kbs later): no tight waitcnts.
// ---------------------------------------------------------------------------
template<int PH, bool LOADN, class F>
__device__ __forceinline__ void mfma_phase(
    const unsigned short* __restrict__ bb,   // this phase's slab + lane offset
    const unsigned short* __restrict__ bn,   // next phase's slab + lane offset
    const unsigned short* __restrict__ aptr, // h tile + lane A-base
    short8 (&bq)[3][4], float4v (&acc)[4][4], F&& other)
{
  short8 a0[4], a1[4];
  #pragma unroll
  for (int mi = 0; mi < 4; ++mi)
    a0[mi] = *(const short8*)(aptr + mi * MISTEP);

  #pragma unroll
  for (int kb = 0; kb < 8; ++kb) {
    short8* cur = (kb & 1) ? a1 : a0;
    short8* nxt = (kb & 1) ? a0 : a1;
    const int slot = (8 * PH + kb) % 3;            // compile-time (unrolled)
    #pragma unroll
    for (int sub = 0; sub < 4; ++sub) {
      // ---- MFMA group: A-frag cur[sub] x 4 B-frags ----
      #pragma unroll
      for (int ni = 0; ni < 4; ++ni)
        acc[sub][ni] = bf16_mfma(cur[sub], bq[slot][ni], acc[sub][ni]);
      // ---- memory-issue slots (same depths as round 2) ----
      if (sub == 1 && kb < 7) {                    // A prefetch depth 1 (LDS)
        #pragma unroll
        for (int mi = 0; mi < 4; ++mi)
          nxt[mi] = *(const short8*)(aptr + (kb + 1) * 32 + mi * MISTEP);
      }
      if (sub == 3) {
        if (kb < 5) {                              // B depth-3, this phase
          #pragma unroll
          for (int ni = 0; ni < 4; ++ni)
            bq[slot][ni] = *(const short8*)(bb + (kb + 3) * 8192 + ni * 512);
        } else if (LOADN) {                        // next phase's kb 0..2
          #pragma unroll
          for (int ni = 0; ni < 4; ++ni)
            bq[slot][ni] = *(const short8*)(bn + (kb - 5) * 8192 + ni * 512);
        }
      }
      __builtin_amdgcn_sched_barrier(0);
      other(kb, sub);                              // ~2 softplus elems (VALU)
      __builtin_amdgcn_sched_barrier(0);
    }
  }
}

// ---------------------------------------------------------------------------
// Fused MLP: one workgroup owns TWO 64-row tiles (128 rows) in anti-phase.
// Each phase: K-loop(tile X, layer l) with tile Y's softplus interleaved
// at substep granularity. 4 waves, wave tile 64m x 64n, one series/block,
// s = blk&7. LDS: 2 x 34304 B tiles + cbuf = 70 KB -> 2 blocks/CU.
// ---------------------------------------------------------------------------
__global__ __launch_bounds__(256, 2) void series_mlp(
    const float* __restrict__ coords,
    const float* __restrict__ W0, const float* __restrict__ b0,
    const float* __restrict__ bh,
    const float* __restrict__ Wout, const float* __restrict__ bout,
    const unsigned short* __restrict__ Wt,
    float* __restrict__ out)
{
  __shared__ __align__(16) unsigned short h_lds[2 * HSIZE];   // 68608 B
  __shared__ float cbuf[384];

  const int tid  = threadIdx.x;
  const int lane = tid & 63;
  const int wave = tid >> 6;
  const int s    = blockIdx.x & 7;           // series == XCD
  const int m0   = (blockIdx.x >> 3) * 128;  // 1563 m-blocks; tail tile1 dead

  const int q    = lane >> 4;
  const int lr   = lane & 15;
  const int colb = (wave << 6) + lr;

  // coords for 128 rows (tail block: clamp index -> finite garbage, unwritten)
  {
    int i1 = m0 * 3 + tid;
    int i2 = i1 + 256;
    cbuf[tid] = coords[i1 < 599999 ? i1 : 599999];
    if (tid < 128) cbuf[tid + 256] = coords[i2 < 599999 ? i2 : 599999];
  }

  // layer-0 weights for this thread's column (shared by both tiles)
  const int c = tid;
  const float w0  = W0[(s * 3 + 0) * 256 + c] * LOG2E;
  const float w1  = W0[(s * 3 + 1) * 256 + c] * LOG2E;
  const float w2  = W0[(s * 3 + 2) * 256 + c] * LOG2E;
  const float bb0 = b0[s * 256 + c] * LOG2E;

  // B-frag lane base + initial 3-slot fill (issued early: hides L2 latency
  // under the layer-0 VALU work)
  const unsigned short* bbase0 = Wt + ((s << 2) << 16) + (colb << 5) + (q << 3);
  short8 bq[3][4];
  #pragma unroll
  for (int i = 0; i < 3; ++i)
    #pragma unroll
    for (int ni = 0; ni < 4; ++ni)
      bq[i][ni] = *(const short8*)(bbase0 + i * 8192 + ni * 512);

  // A-frag / C-write lane bases per tile (round-0 addressing, verbatim)
  const unsigned short* aptrA = h_lds + lr * HSTRIDE + (lr >> 2) * 16 + (q << 3);
  const unsigned short* aptrB = aptrA + HSIZE;
  unsigned short* cptrA = h_lds + q * 1072 + colb;
  unsigned short* cptrB = cptrA + HSIZE;

  const float* bh_s = bh + (s << 10);
  const float4v* c4 = (const float4v*)cbuf;

  __syncthreads();                      // cbuf ready
  #pragma unroll
  for (int j = 0; j < 16; ++j)          // layer 0, tile A (exposed prologue)
    l0_rows(h_lds, c4, j, c, w0, w1, w2, bb0);
  __syncthreads();                      // hA(0) ready

  float4v accA[4][4], accB[4][4];

#define INIT_ACC(ACC, LIDX)                                                   \
  {                                                                           \
    float bias[4];                                                            \
    _Pragma("unroll")                                                         \
    for (int ni = 0; ni < 4; ++ni)                                            \
      bias[ni] = bh_s[(LIDX) * 256 + colb + ni * 16] * LOG2E;                 \
    _Pragma("unroll")                                                         \
    for (int mi = 0; mi < 4; ++mi)                                            \
      _Pragma("unroll")                                                       \
      for (int ni = 0; ni < 4; ++ni)                                          \
        ACC[mi][ni] = (float4v){bias[ni], bias[ni], bias[ni], bias[ni]};      \
  }

  const unsigned short* B0 = bbase0;
  const unsigned short* B1 = bbase0 + 65536;
  const unsigned short* B2 = bbase0 + 2 * 65536;
  const unsigned short* B3 = bbase0 + 3 * 65536;

  // P0: K(tA, l0) || layer-0 for tile B (one row-quad on subs 0 and 2)
  INIT_ACC(accA, 0)
  mfma_phase<0, true>(B0, B0, aptrA, bq, accA, [&](int kb, int sub){
    if (sub == 0) l0_rows(h_lds + HSIZE, c4 + 48, 2 * kb + 0, c, w0, w1, w2, bb0);
    if (sub == 2) l0_rows(h_lds + HSIZE, c4 + 48, 2 * kb + 1, c, w0, w1, w2, bb0);
  });
  __syncthreads();                      // hB(0) ready

  // P1: K(tB, l0) || softplus(accA) -> hA(1)
  INIT_ACC(accB, 0)
  mfma_phase<1, true>(B0, B1, aptrB, bq, accB,
      [&](int kb, int sub){ sp2s(accA, cptrA, kb, sub); });
  __syncthreads();                      // hA(1) ready

  // P2: K(tA, l1) || softplus(accB) -> hB(1)
  INIT_ACC(accA, 1)
  mfma_phase<2, true>(B1, B1, aptrA, bq, accA,
      [&](int kb, int sub){ sp2s(accB, cptrB, kb, sub); });
  __syncthreads();                      // hB(1) ready

  // P3: K(tB, l1) || softplus(accA) -> hA(2)
  INIT_ACC(accB, 1)
  mfma_phase<3, true>(B1, B2, aptrB, bq, accB,
      [&](int kb, int sub){ sp2s(accA, cptrA, kb, sub); });
  __syncthreads();                      // hA(2) ready

  // P4: K(tA, l2) || softplus(accB) -> hB(2)
  INIT_ACC(accA, 2)
  mfma_phase<4, true>(B2, B2, aptrA, bq, accA,
      [&](int kb, int sub){ sp2s(accB, cptrB, kb, sub); });
  __syncthreads();                      // hB(2) ready

  // P5: K(tB, l2) || softplus(accA) -> hA(3)
  INIT_ACC(accB, 2)
  mfma_phase<5, true>(B2, B3, aptrB, bq, accB,
      [&](int kb, int sub){ sp2s(accA, cptrA, kb, sub); });
  __syncthreads();                      // hA(3) ready

  // P6: K(tA, l3) || softplus(accB) -> hB(3)
  INIT_ACC(accA, 3)
  mfma_phase<6, true>(B3, B3, aptrA, bq, accA,
      [&](int kb, int sub){ sp2s(accB, cptrB, kb, sub); });
  __syncthreads();                      // hB(3) ready

  // P7: K(tB, l3) || softplus+output-dot of accA
  INIT_ACC(accB, 3)
  float wv[4];
  #pragma unroll
  for (int ni = 0; ni < 4; ++ni)
    wv[ni] = Wout[(s << 8) + colb + ni * 16];
  float pA[16], pB[16];
  #pragma unroll
  for (int i = 0; i < 16; ++i) pA[i] = 0.f;
  mfma_phase<7, false>(B3, B3, aptrB, bq, accB,
      [&](int kb, int sub){ spdot2s(accA, wv, pA, kb, sub); });

  #pragma unroll
  for (int i = 0; i < 16; ++i) pB[i] = 0.f;
  #pragma unroll
  for (int kb = 0; kb < 8; ++kb)        // tile B's dot (exposed epilogue)
    #pragma unroll
    for (int sub = 0; sub < 4; ++sub)
      spdot2s(accB, wv, pB, kb, sub);

  // cross-wave reduce: 2 regions of 64 rows x 64 partials (stride-68 pad).
  // Barrier first: other waves may still be doing P7 A-reads from hB.
  __syncthreads();
  float* redA = (float*)h_lds;
  float* redB = redA + 64 * 68;
  #pragma unroll
  for (int mi = 0; mi < 4; ++mi)
    #pragma unroll
    for (int r = 0; r < 4; ++r) {
      int row = mi * 16 + (q << 2) + r;
      redA[row * 68 + (wave << 4) + lr] = pA[mi * 4 + r];
      redB[row * 68 + (wave << 4) + lr] = pB[mi * 4 + r];
    }
  __syncthreads();

  if (tid < 128) {
    const int t = tid & 63;
    const float* red = (tid < 64) ? redA : redB;
    const float4v* rr = (const float4v*)&red[t * 68];
    float4v a = rr[0];
    #pragma unroll
    for (int i = 1; i < 16; ++i) {
      float4v b = rr[i];
      a.x += b.x; a.y += b.y; a.z += b.z; a.w += b.w;
    }
    float tot = (a.x + a.y) + (a.z + a.w);
    int row = m0 + ((tid >> 6) << 6) + t;
    if (row < 200000)
      out[row * 8 + s] = fmaf(LN2, tot, bout[s]);  // undo log2-domain
  }
#undef INIT_ACC
}

// ---------------------------------------------------------------------------
// Fallback (scratch-free), fp32 VALU — only if ws_size < 4 MiB.
// ---------------------------------------------------------------------------
__global__ __launch_bounds__(256) void series_mlp_slow(
    const float* __restrict__ coords,
    const float* __restrict__ W0, const float* __restrict__ b0,
    const float* __restrict__ Wh, const float* __restrict__ bh,
    const float* __restrict__ Wout, const float* __restrict__ bout,
    float* __restrict__ out)
{
  __shared__ float hh[64 * 256];
  __shared__ float cbuf[192];
  __shared__ float red[256];
  const int tid = threadIdx.x;
  const int s   = blockIdx.y;
  const int m0  = blockIdx.x * 64;

  if (tid < 192) cbuf[tid] = coords[m0 * 3 + tid];
  __syncthreads();
  {
    const float w0 = W0[(s * 3 + 0) * 256 + tid];
    const float w1 = W0[(s * 3 + 1) * 256 + tid];
    const float w2 = W0[(s * 3 + 2) * 256 + tid];
    const float bb = b0[s * 256 + tid];
    for (int m = 0; m < 64; ++m) {
      float z = fmaf(cbuf[m * 3 + 2], w2,
                fmaf(cbuf[m * 3 + 1], w1,
                fmaf(cbuf[m * 3 + 0], w0, bb)));
      hh[m * 256 + tid] = LN2 * softplus_hat(z * LOG2E);
    }
  }
  __syncthreads();

  for (int l = 0; l < 4; ++l) {
    const float* W = Wh + (((s << 2) + l) << 16);
    const float bb = bh[((s << 2) + l) * 256 + tid];
    float acc[64];
    #pragma unroll
    for (int m = 0; m < 64; ++m) acc[m] = bb;
    for (int kc = 0; kc < 64; ++kc) {
      float w0 = W[(kc * 4 + 0) * 256 + tid];
      float w1 = W[(kc * 4 + 1) * 256 + tid];
      float w2 = W[(kc * 4 + 2) * 256 + tid];
      float w3 = W[(kc * 4 + 3) * 256 + tid];
      #pragma unroll
      for (int m = 0; m < 64; ++m) {
        float4v hv = *(const float4v*)&hh[m * 256 + kc * 4];
        acc[m] = fmaf(hv.w, w3, fmaf(hv.z, w2,
                 fmaf(hv.y, w1, fmaf(hv.x, w0, acc[m]))));
      }
    }
    __syncthreads();
    #pragma unroll
    for (int m = 0; m < 64; ++m)
      hh[m * 256 + tid] = LN2 * softplus_hat(acc[m] * LOG2E);
    __syncthreads();
  }
  {
    const int m = tid >> 2, qq = tid & 3;
    const float* wv = Wout + (s << 8);
    float sum = 0.f;
    for (int i = 0; i < 16; ++i) {
      int kk = (qq << 6) + ((((tid & 15) + i) << 2) & 63);
      float4v hv = *(const float4v*)&hh[m * 256 + kk];
      sum += hv.x * wv[kk] + hv.y * wv[kk + 1] + hv.z * wv[kk + 2] + hv.w * wv[kk + 3];
    }
    red[tid] = sum;
    __syncthreads();
    if (tid < 64)
      out[(m0 + tid) * 8 + s] =
          red[tid * 4] + red[tid * 4 + 1] + red[tid * 4 + 2] + red[tid * 4 + 3] + bout[s];
  }
}

extern "C" void kernel_launch(void* const* d_in, const int* in_sizes, int n_in,
                              void* d_out, int out_size, void* d_ws, size_t ws_size,
                              hipStream_t stream) {
  const float* coords = (const float*)d_in[0];
  const float* W0     = (const float*)d_in[1];
  const float* b0     = (const float*)d_in[2];
  const float* Wh     = (const float*)d_in[3];
  const float* bh     = (const float*)d_in[4];
  const float* Wout   = (const float*)d_in[5];
  const float* bout   = (const float*)d_in[6];
  float* out = (float*)d_out;

  const size_t WT_BYTES = (size_t)8 * 4 * 256 * 256 * 2;   // 4 MiB bf16 slabs
  if (ws_size >= WT_BYTES) {
    unsigned short* Wt = (unsigned short*)d_ws;
    convert_wh<<<8192, 256, 0, stream>>>(Wh, Wt);
    // 1563 m-blocks x 128 rows x 8 series; 1562*128+64 = 200000 (tail tile1 dead)
    series_mlp<<<dim3(12504), dim3(256), 0, stream>>>(
        coords, W0, b0, bh, Wout, bout, Wt, out);
  } else {
    series_mlp_slow<<<dim3(3125, 8), dim3(256), 0, stream>>>(
        coords, W0, b0, Wh, bh, Wout, bout, out);
  }
  // second tuple output: echo coords
  hipMemcpyAsync(out + (size_t)200000 * 8, coords,
                 (size_t)200000 * 3 * sizeof(float),
                 hipMemcpyDeviceToDevice, stream);
}